// Round 4
// baseline (466.053 us; speedup 1.0000x reference)
//
#include <hip/hip_runtime.h>
#include <climits>
#include <cstdint>

// Round 6: identical to R4/R5 (four consecutive broker timeouts -- the
// flat-streamer has never executed; no new evidence, no speculative edits).
// Flat streaming coarse kernel: grid-stride 2048x256, 4x float4 in flight per
// thread, per-block partial sums, scattered atomicMin for the rare jv updates
// (~1 per row, distinct addresses -- NOT R1's same-line atomic failure mode).
// gt (268 MB) is the only unavoidable HBM stream; floor ~43 us at 6.3 TB/s.
// R2's 492.5 us = per-row wave structure choking occupancy/MLP (~0.55 TB/s).
//
// ws layout (bytes):
//   [0,        M*4)          int   jv[B*L]   min col with gt>0, sentinel 0x7F7F7F7F
//   [M*4,      M*4+N*4)      float pnbuf[N]  pn if (found && pn<10) else -1
//   [M*4+N*4,  +CGRID*4)     float partial[CGRID] per-block coarse sums

typedef float f32x4 __attribute__((ext_vector_type(4)));

static constexpr int CGRID = 2048;

template <int LSHIFT>
__device__ __forceinline__ void coarse_proc4(
    float& local, const float* __restrict__ cm, int* __restrict__ jv,
    const f32x4 g, const unsigned v)
{
    constexpr unsigned LMASK = (1u << LSHIFT) - 1u;
    const unsigned e   = v << 2;          // element index (float4-aligned)
    const unsigned row = e >> LSHIFT;     // all 4 elems same row (L % 4 == 0)
    const unsigned col = e & LMASK;
    #pragma unroll
    for (int k = 0; k < 4; ++k) {
        const float gk = g[k];
        if (gk != 0.0f) {
            local += gk * logf(__builtin_nontemporal_load(&cm[e + k]) + 1e-6f);
            if (gk > 0.0f) atomicMin(&jv[row], (int)(col + (unsigned)k));
        }
    }
}

__device__ __forceinline__ void coarse_proc4_gen(
    float& local, const float* __restrict__ cm, int* __restrict__ jv,
    const f32x4 g, const unsigned v, const unsigned L)
{
    const unsigned e   = v << 2;
    const unsigned row = e / L;
    const unsigned col = e - row * L;
    #pragma unroll
    for (int k = 0; k < 4; ++k) {
        const float gk = g[k];
        if (gk != 0.0f) {
            local += gk * logf(__builtin_nontemporal_load(&cm[e + k]) + 1e-6f);
            if (gk > 0.0f) atomicMin(&jv[row], (int)(col + (unsigned)k));
        }
    }
}

template <int LSHIFT>
__global__ __launch_bounds__(256) void mc_coarse_flat(
    const float* __restrict__ cm, const float* __restrict__ gt,
    unsigned nvec, int* __restrict__ jv, float* __restrict__ partial)
{
    const unsigned stride = gridDim.x * blockDim.x;
    unsigned v = blockIdx.x * blockDim.x + threadIdx.x;
    const f32x4* __restrict__ g4 = reinterpret_cast<const f32x4*>(gt);

    float local = 0.0f;

    // main loop: 4 float4 loads in flight per thread, fully coalesced,
    // nontemporal (gt is a one-shot 268 MB stream -- don't thrash L2/L3).
    for (; v + 3u * stride < nvec; v += 4u * stride) {
        const f32x4 ga = __builtin_nontemporal_load(&g4[v]);
        const f32x4 gb = __builtin_nontemporal_load(&g4[v + stride]);
        const f32x4 gc = __builtin_nontemporal_load(&g4[v + 2u * stride]);
        const f32x4 gd = __builtin_nontemporal_load(&g4[v + 3u * stride]);
        coarse_proc4<LSHIFT>(local, cm, jv, ga, v);
        coarse_proc4<LSHIFT>(local, cm, jv, gb, v + stride);
        coarse_proc4<LSHIFT>(local, cm, jv, gc, v + 2u * stride);
        coarse_proc4<LSHIFT>(local, cm, jv, gd, v + 3u * stride);
    }
    for (; v < nvec; v += stride) {
        const f32x4 g = __builtin_nontemporal_load(&g4[v]);
        coarse_proc4<LSHIFT>(local, cm, jv, g, v);
    }

    #pragma unroll
    for (int o = 32; o; o >>= 1) local += __shfl_down(local, o);
    __shared__ float sc[4];
    if ((threadIdx.x & 63) == 0) sc[threadIdx.x >> 6] = local;
    __syncthreads();
    if (threadIdx.x == 0) partial[blockIdx.x] = sc[0] + sc[1] + sc[2] + sc[3];
}

__global__ __launch_bounds__(256) void mc_coarse_flat_gen(
    const float* __restrict__ cm, const float* __restrict__ gt,
    unsigned nvec, unsigned L, int* __restrict__ jv, float* __restrict__ partial)
{
    const unsigned stride = gridDim.x * blockDim.x;
    unsigned v = blockIdx.x * blockDim.x + threadIdx.x;
    const f32x4* __restrict__ g4 = reinterpret_cast<const f32x4*>(gt);

    float local = 0.0f;
    for (; v + 3u * stride < nvec; v += 4u * stride) {
        const f32x4 ga = __builtin_nontemporal_load(&g4[v]);
        const f32x4 gb = __builtin_nontemporal_load(&g4[v + stride]);
        const f32x4 gc = __builtin_nontemporal_load(&g4[v + 2u * stride]);
        const f32x4 gd = __builtin_nontemporal_load(&g4[v + 3u * stride]);
        coarse_proc4_gen(local, cm, jv, ga, v, L);
        coarse_proc4_gen(local, cm, jv, gb, v + stride, L);
        coarse_proc4_gen(local, cm, jv, gc, v + 2u * stride, L);
        coarse_proc4_gen(local, cm, jv, gd, v + 3u * stride, L);
    }
    for (; v < nvec; v += stride) {
        const f32x4 g = __builtin_nontemporal_load(&g4[v]);
        coarse_proc4_gen(local, cm, jv, g, v, L);
    }

    #pragma unroll
    for (int o = 32; o; o >>= 1) local += __shfl_down(local, o);
    __shared__ float sc[4];
    if ((threadIdx.x & 63) == 0) sc[threadIdx.x >> 6] = local;
    __syncthreads();
    if (threadIdx.x == 0) partial[blockIdx.x] = sc[0] + sc[1] + sc[2] + sc[3];
}

// ---------- fine: one 256-thread block per point (4 waves cut exposed L2
// latency 4x vs the old 64-thread version); result to pnbuf, no atomics ----
__global__ __launch_bounds__(256) void mc_fine_kernel(
    const float* __restrict__ s0, const float* __restrict__ s1,
    const float* __restrict__ mk0, const float* __restrict__ mk1,
    const int* __restrict__ jv, int B, int L,
    float* __restrict__ pnbuf)
{
    const int n = blockIdx.x;
    const float bf = mk0[3 * n + 0];
    const float x  = mk0[3 * n + 1];
    const float y  = mk0[3 * n + 2];
    const int b = (int)bf;

    int best = INT_MAX;
    if ((float)b == bf && b >= 0 && b < B) {
        const float2* __restrict__ srow = reinterpret_cast<const float2*>(s0 + (size_t)b * L * 2);
        const int*    __restrict__ jrow = jv + (size_t)b * L;
        #pragma unroll 4
        for (int i = threadIdx.x; i < L; i += 256) {
            const float2 s = srow[i];
            if (s.x == x && s.y == y && jrow[i] < L) best = min(best, i);
        }
    }
    #pragma unroll
    for (int o = 32; o; o >>= 1) best = min(best, __shfl_down(best, o));

    __shared__ int sb[4];
    if ((threadIdx.x & 63) == 0) sb[threadIdx.x >> 6] = best;
    __syncthreads();

    if (threadIdx.x == 0) {
        best = min(min(sb[0], sb[1]), min(sb[2], sb[3]));
        float res = -1.0f;
        if (best != INT_MAX) {
            const int j = jv[(size_t)b * L + best];
            const float gx = s1[((size_t)b * L + j) * 2 + 0];
            const float gy = s1[((size_t)b * L + j) * 2 + 1];
            const float dx = gx - mk1[2 * n + 0];
            const float dy = gy - mk1[2 * n + 1];
            const float pn = sqrtf(dx * dx + dy * dy);
            if (pn < 10.0f) res = pn;
        }
        pnbuf[n] = res;
    }
}

// ---------- finalize: reduce block partials, jv validity, pnbuf ----------
__global__ __launch_bounds__(1024) void mc_finalize_kernel(
    const float* __restrict__ partial, int P,
    const int* __restrict__ jv, int M,
    const float* __restrict__ pnbuf, int N,
    float binv, int L, float* __restrict__ out)
{
    float csum = 0.0f, fsum = 0.0f;
    int vcnt = 0, fcnt = 0;
    for (int i = threadIdx.x; i < P; i += 1024) csum += partial[i];
    for (int i = threadIdx.x; i < M; i += 1024) vcnt += (jv[i] < L) ? 1 : 0;
    for (int i = threadIdx.x; i < N; i += 1024) {
        const float p = pnbuf[i];
        if (p >= 0.0f) { fsum += p; ++fcnt; }
    }
    #pragma unroll
    for (int o = 32; o; o >>= 1) {
        csum += __shfl_down(csum, o);
        vcnt += __shfl_down(vcnt, o);
        fsum += __shfl_down(fsum, o);
        fcnt += __shfl_down(fcnt, o);
    }
    __shared__ float sc[16], sf[16];
    __shared__ int   sv[16], sn[16];
    const int wid = threadIdx.x >> 6, lane = threadIdx.x & 63;
    if (lane == 0) { sc[wid] = csum; sv[wid] = vcnt; sf[wid] = fsum; sn[wid] = fcnt; }
    __syncthreads();
    if (threadIdx.x == 0) {
        float C = 0.0f, F = 0.0f; int V = 0, K = 0;
        const int nw = blockDim.x >> 6;
        for (int w = 0; w < nw; ++w) { C += sc[w]; V += sv[w]; F += sf[w]; K += sn[w]; }
        const float coarse = -C * binv;
        const float fine = (V > 0) ? ((K > 0) ? F / (float)K : 10.0f) : 1e-6f;
        out[0] = coarse + 1000.0f * fine;
        out[1] = coarse;
        out[2] = fine;
    }
}

extern "C" void kernel_launch(void* const* d_in, const int* in_sizes, int n_in,
                              void* d_out, int out_size, void* d_ws, size_t ws_size,
                              hipStream_t stream) {
    const float* cm  = (const float*)d_in[0];  // [B,L,L]
    const float* gt  = (const float*)d_in[1];  // [B,L,L]
    const float* s0  = (const float*)d_in[2];  // [B,L,2]
    const float* s1  = (const float*)d_in[3];  // [B,L,2]
    const float* mk0 = (const float*)d_in[4];  // [N,3]
    const float* mk1 = (const float*)d_in[5];  // [N,2]
    float* out = (float*)d_out;

    // in_sizes are ELEMENT counts (verified: both L and N derivations agree
    // only under this interpretation).
    const int L = 2 * (in_sizes[0] / in_sizes[2]);
    const int B = in_sizes[2] / (2 * L);
    const int N = in_sizes[4] / 3;
    const int M = B * L;
    const unsigned nvec = (unsigned)(in_sizes[0] >> 2);  // float4 count of gt

    int*   jv      = (int*)d_ws;
    float* pnbuf   = (float*)((char*)d_ws + (size_t)M * 4);
    float* partial = (float*)((char*)d_ws + (size_t)M * 4 + (size_t)N * 4);

    // jv sentinel: 0x7F7F7F7F > any col; "valid" test everywhere is jv < L.
    hipMemsetAsync(jv, 0x7F, (size_t)M * 4, stream);

    if (L == 4096) {
        mc_coarse_flat<12><<<CGRID, 256, 0, stream>>>(cm, gt, nvec, jv, partial);
    } else {
        mc_coarse_flat_gen<<<CGRID, 256, 0, stream>>>(cm, gt, nvec, (unsigned)L, jv, partial);
    }
    mc_fine_kernel<<<N, 256, 0, stream>>>(s0, s1, mk0, mk1, jv, B, L, pnbuf);
    mc_finalize_kernel<<<1, 1024, 0, stream>>>(partial, CGRID, jv, M, pnbuf, N,
                                               1.0f / (float)B, L, out);
}